// Round 14
// baseline (480.579 us; speedup 1.0000x reference)
//
#include <hip/hip_runtime.h>
#include <math.h>

#define BB 8
#define LL 2048
#define DMODEL 128
#define NHEAD 4
#define DHEAD 32
#define DIN 256
#define DSTATE 16
#define NLAYERS 6
#define BLROWS (BB*LL)   // 16384
#define NCHUNK 32
#define CH 64            // scan chunk length

typedef __attribute__((ext_vector_type(8))) short short8;
typedef __attribute__((ext_vector_type(4))) float f32x4;

static __device__ __forceinline__ unsigned cvt_pk_bf16(float a, float b) {
    unsigned r;
    asm volatile("v_cvt_pk_bf16_f32 %0, %1, %2" : "=v"(r) : "v"(a), "v"(b));
    return r;
}
// raw v_exp_f32 (2^x): 1 instruction; args bounded -> OCML clamp is overhead.
static __device__ __forceinline__ float fexp2(float x) {
    float r;
    asm("v_exp_f32 %0, %1" : "=v"(r) : "v"(x));
    return r;
}

// ---------------- weight fp32 -> bf16 preconversion ----------------
__global__ __launch_bounds__(256) void wcvt_k(
    const float* __restrict__ src, ushort* __restrict__ dst, int n4)
{
    int i = blockIdx.x * 256 + threadIdx.x;
    if (i < n4) {
        float4 v = ((const float4*)src)[i];
        uint2 pw; pw.x = cvt_pk_bf16(v.x, v.y); pw.y = cvt_pk_bf16(v.z, v.w);
        ((uint2*)dst)[i] = pw;
    }
}

// ---------------- mlp1 + positional encoding ----------------
__global__ __launch_bounds__(256) void mlp1_pe_k(
    const float* __restrict__ x, const float* __restrict__ w,
    const float* __restrict__ b, float* __restrict__ h)
{
    int idx = blockIdx.x * 256 + threadIdx.x;   // over BLROWS*128
    int d   = idx & 127;
    int row = idx >> 7;
    int pos = row & (LL - 1);
    float v = x[row] * w[d] + b[d];
    int j2 = (d >> 1) * 2;
    float dv = expf((float)j2 * -0.07195578415603638f);
    float ang = (float)pos * dv;
    v += (d & 1) ? cosf(ang) : sinf(ang);
    h[idx] = v;
}

// ---------------- qkv GEMM: bf16 out, q pre-scaled: C16[M,384] ----------------
#define QSCALE (0.17677669529663687f * 1.4426950408889634f)   // 1/sqrt(32) * log2(e)
__global__ __launch_bounds__(256) void gemm_qkv_k(
    const float* __restrict__ A, const ushort* __restrict__ W16,
    const float* __restrict__ bias, ushort* __restrict__ C16)
{
    __shared__ __align__(16) short As[64][136];
    __shared__ __align__(16) short Ws[128][136];
    int tid = threadIdx.x;
    int w = tid >> 6, lane = tid & 63, lg = lane >> 4, lr = lane & 15;
    int row0 = blockIdx.y * 64, col0 = blockIdx.x * 128;

    const float* Ab = A + (size_t)row0 * 128;
    #pragma unroll
    for (int p = 0; p < 8; ++p) {
        int off = p * 1024 + tid * 4;
        float4 v = *(const float4*)(Ab + off);
        uint2 pw; pw.x = cvt_pk_bf16(v.x, v.y); pw.y = cvt_pk_bf16(v.z, v.w);
        *(uint2*)&As[off >> 7][off & 127] = pw;
    }
    const ushort* Wb = W16 + (size_t)col0 * 128;
    #pragma unroll
    for (int p = 0; p < 8; ++p) {
        int off = p * 2048 + tid * 8;
        short8 v = *(const short8*)(Wb + off);
        *(short8*)&Ws[off >> 7][off & 127] = v;
    }
    __syncthreads();

    short8 af[4];
    #pragma unroll
    for (int kk = 0; kk < 4; ++kk)
        af[kk] = *(short8*)&As[w * 16 + lr][kk * 32 + lg * 8];
    f32x4 acc[8];
    #pragma unroll
    for (int n = 0; n < 8; ++n) acc[n] = (f32x4){0.f, 0.f, 0.f, 0.f};
    #pragma unroll
    for (int n = 0; n < 8; ++n)
        #pragma unroll
        for (int kk = 0; kk < 4; ++kk) {
            short8 bf = *(short8*)&Ws[n * 16 + lr][kk * 32 + lg * 8];
            acc[n] = __builtin_amdgcn_mfma_f32_16x16x32_bf16(af[kk], bf, acc[n], 0, 0, 0);
        }
    float qs = (blockIdx.x == 0) ? QSCALE : 1.f;
    #pragma unroll
    for (int n = 0; n < 8; ++n) {
        int col = col0 + n * 16 + lr;
        float bv = bias[col];
        #pragma unroll
        for (int j = 0; j < 4; ++j) {
            int row = row0 + w * 16 + lg * 4 + j;
            float v = (acc[n][j] + bv) * qs;
            C16[(size_t)row * 384 + col] = (ushort)cvt_pk_bf16(v, v);
        }
    }
}

// ---------------- bf16 MFMA GEMM (in_proj): C[M,N] = A[M,128] @ W[N,128]^T ----------------
__global__ __launch_bounds__(256) void gemm_bf16_k(
    const float* __restrict__ A, const ushort* __restrict__ W16,
    float* __restrict__ C, int N)
{
    __shared__ __align__(16) short As[64][136];
    __shared__ __align__(16) short Ws[128][136];
    int tid = threadIdx.x;
    int w = tid >> 6, lane = tid & 63, lg = lane >> 4, lr = lane & 15;
    int row0 = blockIdx.y * 64, col0 = blockIdx.x * 128;

    const float* Ab = A + (size_t)row0 * 128;
    #pragma unroll
    for (int p = 0; p < 8; ++p) {
        int off = p * 1024 + tid * 4;
        float4 v = *(const float4*)(Ab + off);
        uint2 pw; pw.x = cvt_pk_bf16(v.x, v.y); pw.y = cvt_pk_bf16(v.z, v.w);
        *(uint2*)&As[off >> 7][off & 127] = pw;
    }
    const ushort* Wb = W16 + (size_t)col0 * 128;
    #pragma unroll
    for (int p = 0; p < 8; ++p) {
        int off = p * 2048 + tid * 8;
        short8 v = *(const short8*)(Wb + off);
        *(short8*)&Ws[off >> 7][off & 127] = v;
    }
    __syncthreads();

    short8 af[4];
    #pragma unroll
    for (int kk = 0; kk < 4; ++kk)
        af[kk] = *(short8*)&As[w * 16 + lr][kk * 32 + lg * 8];
    f32x4 acc[8];
    #pragma unroll
    for (int n = 0; n < 8; ++n) acc[n] = (f32x4){0.f, 0.f, 0.f, 0.f};
    #pragma unroll
    for (int n = 0; n < 8; ++n)
        #pragma unroll
        for (int kk = 0; kk < 4; ++kk) {
            short8 bf = *(short8*)&Ws[n * 16 + lr][kk * 32 + lg * 8];
            acc[n] = __builtin_amdgcn_mfma_f32_16x16x32_bf16(af[kk], bf, acc[n], 0, 0, 0);
        }
    #pragma unroll
    for (int n = 0; n < 8; ++n) {
        int col = col0 + n * 16 + lr;
        #pragma unroll
        for (int j = 0; j < 4; ++j) {
            int row = row0 + w * 16 + lg * 4 + j;
            C[(size_t)row * N + col] = acc[n][j];
        }
    }
}

// ---------------- fused GEMM(N=128) + residual + LayerNorm (A bf16, W bf16) ----------------
__global__ __launch_bounds__(256) void gemm_ln_k(
    const ushort* __restrict__ A16, const ushort* __restrict__ W16,
    const float* __restrict__ bias, float* __restrict__ h,
    const float* __restrict__ ls, const float* __restrict__ lb)
{
    __shared__ __align__(16) short As[64][136];
    __shared__ __align__(16) short Ws[128][136];
    int tid = threadIdx.x;
    int w = tid >> 6, lane = tid & 63, lg = lane >> 4, lr = lane & 15;
    int row0 = blockIdx.x * 64;

    const ushort* Ab = A16 + (size_t)row0 * 128;
    #pragma unroll
    for (int p = 0; p < 4; ++p) {
        int off = p * 2048 + tid * 8;
        short8 v = *(const short8*)(Ab + off);
        *(short8*)&As[off >> 7][off & 127] = v;
    }
    #pragma unroll
    for (int p = 0; p < 8; ++p) {
        int off = p * 2048 + tid * 8;
        short8 v = *(const short8*)(W16 + off);
        *(short8*)&Ws[off >> 7][off & 127] = v;
    }
    __syncthreads();

    short8 af[4];
    #pragma unroll
    for (int kk = 0; kk < 4; ++kk)
        af[kk] = *(short8*)&As[w * 16 + lr][kk * 32 + lg * 8];
    f32x4 acc[8];
    #pragma unroll
    for (int n = 0; n < 8; ++n) acc[n] = (f32x4){0.f, 0.f, 0.f, 0.f};
    #pragma unroll
    for (int n = 0; n < 8; ++n)
        #pragma unroll
        for (int kk = 0; kk < 4; ++kk) {
            short8 bf = *(short8*)&Ws[n * 16 + lr][kk * 32 + lg * 8];
            acc[n] = __builtin_amdgcn_mfma_f32_16x16x32_bf16(af[kk], bf, acc[n], 0, 0, 0);
        }

    float bv[8], lsv[8], lbv[8];
    #pragma unroll
    for (int n = 0; n < 8; ++n) {
        int col = n * 16 + lr;
        bv[n] = bias[col]; lsv[n] = ls[col]; lbv[n] = lb[col];
    }
    #pragma unroll
    for (int j = 0; j < 4; ++j) {
        int row = row0 + w * 16 + lg * 4 + j;
        float xv[8]; float sum = 0.f;
        #pragma unroll
        for (int n = 0; n < 8; ++n) {
            xv[n] = acc[n][j] + bv[n] + h[(size_t)row * 128 + n * 16 + lr];
            sum += xv[n];
        }
        sum += __shfl_xor(sum, 1); sum += __shfl_xor(sum, 2);
        sum += __shfl_xor(sum, 4); sum += __shfl_xor(sum, 8);
        float mean = sum * (1.f / 128.f);
        float vs = 0.f;
        #pragma unroll
        for (int n = 0; n < 8; ++n) { float dd = xv[n] - mean; vs += dd * dd; }
        vs += __shfl_xor(vs, 1); vs += __shfl_xor(vs, 2);
        vs += __shfl_xor(vs, 4); vs += __shfl_xor(vs, 8);
        float inv = rsqrtf(vs * (1.f / 128.f) + 1e-5f);
        #pragma unroll
        for (int n = 0; n < 8; ++n)
            h[(size_t)row * 128 + n * 16 + lr] = (xv[n] - mean) * inv * lsv[n] + lbv[n];
    }
}

// ---------------- fused FFW (w1+relu+w2) + residual + LayerNorm (W bf16) ----------------
__global__ __launch_bounds__(256) void ffw_ln_k(
    float* __restrict__ h, const ushort* __restrict__ W1, const float* __restrict__ b1,
    const ushort* __restrict__ W2, const float* __restrict__ b2,
    const float* __restrict__ ls, const float* __restrict__ lb)
{
    __shared__ __align__(16) short As[64][136];
    __shared__ __align__(16) short Ws[128][136];
    int tid = threadIdx.x;
    int w = tid >> 6, lane = tid & 63, lg = lane >> 4, lr = lane & 15;
    int row0 = blockIdx.x * 64;

    const float* Ab = h + (size_t)row0 * 128;
    #pragma unroll
    for (int p = 0; p < 8; ++p) {
        int off = p * 1024 + tid * 4;
        float4 v = *(const float4*)(Ab + off);
        uint2 pw; pw.x = cvt_pk_bf16(v.x, v.y); pw.y = cvt_pk_bf16(v.z, v.w);
        *(uint2*)&As[off >> 7][off & 127] = pw;
    }
    #pragma unroll
    for (int p = 0; p < 8; ++p) {
        int off = p * 2048 + tid * 8;
        short8 v = *(const short8*)(W1 + off);
        *(short8*)&Ws[off >> 7][off & 127] = v;
    }
    __syncthreads();

    short8 af[4];
    #pragma unroll
    for (int kk = 0; kk < 4; ++kk)
        af[kk] = *(short8*)&As[w * 16 + lr][kk * 32 + lg * 8];
    f32x4 acc[8];
    #pragma unroll
    for (int n = 0; n < 8; ++n) acc[n] = (f32x4){0.f, 0.f, 0.f, 0.f};
    #pragma unroll
    for (int n = 0; n < 8; ++n)
        #pragma unroll
        for (int kk = 0; kk < 4; ++kk) {
            short8 bf = *(short8*)&Ws[n * 16 + lr][kk * 32 + lg * 8];
            acc[n] = __builtin_amdgcn_mfma_f32_16x16x32_bf16(af[kk], bf, acc[n], 0, 0, 0);
        }
    __syncthreads();

    {
        float b1v[8];
        #pragma unroll
        for (int n = 0; n < 8; ++n) b1v[n] = b1[n * 16 + lr];
        #pragma unroll
        for (int n = 0; n < 8; ++n) {
            #pragma unroll
            for (int j = 0; j < 4; ++j) {
                float hv = fmaxf(acc[n][j] + b1v[n], 0.f);
                As[w * 16 + lg * 4 + j][n * 16 + lr] = (short)cvt_pk_bf16(hv, hv);
            }
        }
    }
    #pragma unroll
    for (int p = 0; p < 8; ++p) {
        int off = p * 2048 + tid * 8;
        short8 v = *(const short8*)(W2 + off);
        *(short8*)&Ws[off >> 7][off & 127] = v;
    }
    __syncthreads();

    #pragma unroll
    for (int kk = 0; kk < 4; ++kk)
        af[kk] = *(short8*)&As[w * 16 + lr][kk * 32 + lg * 8];
    #pragma unroll
    for (int n = 0; n < 8; ++n) acc[n] = (f32x4){0.f, 0.f, 0.f, 0.f};
    #pragma unroll
    for (int n = 0; n < 8; ++n)
        #pragma unroll
        for (int kk = 0; kk < 4; ++kk) {
            short8 bf = *(short8*)&Ws[n * 16 + lr][kk * 32 + lg * 8];
            acc[n] = __builtin_amdgcn_mfma_f32_16x16x32_bf16(af[kk], bf, acc[n], 0, 0, 0);
        }

    float bv[8], lsv[8], lbv[8];
    #pragma unroll
    for (int n = 0; n < 8; ++n) {
        int col = n * 16 + lr;
        bv[n] = b2[col]; lsv[n] = ls[col]; lbv[n] = lb[col];
    }
    #pragma unroll
    for (int j = 0; j < 4; ++j) {
        int row = row0 + w * 16 + lg * 4 + j;
        float xv[8]; float sum = 0.f;
        #pragma unroll
        for (int n = 0; n < 8; ++n) {
            xv[n] = acc[n][j] + bv[n] + h[(size_t)row * 128 + n * 16 + lr];
            sum += xv[n];
        }
        sum += __shfl_xor(sum, 1); sum += __shfl_xor(sum, 2);
        sum += __shfl_xor(sum, 4); sum += __shfl_xor(sum, 8);
        float mean = sum * (1.f / 128.f);
        float vs = 0.f;
        #pragma unroll
        for (int n = 0; n < 8; ++n) { float dd = xv[n] - mean; vs += dd * dd; }
        vs += __shfl_xor(vs, 1); vs += __shfl_xor(vs, 2);
        vs += __shfl_xor(vs, 4); vs += __shfl_xor(vs, 8);
        float inv = rsqrtf(vs * (1.f / 128.f) + 1e-5f);
        #pragma unroll
        for (int n = 0; n < 8; ++n)
            h[(size_t)row * 128 + n * 16 + lr] = (xv[n] - mean) * inv * lsv[n] + lbv[n];
    }
}

// ---------------- MFMA bf16 flash attention, KV-split x2 ----------------
// R12's validated loop (swizzled K/V LDS, reg-P, 32 q/wave, double buffer,
// raw v_exp_f32) over HALF the keys per block; fp32 partials merged by
// attn_merge_k (no-max softmax => additive). grid 1024 = {half, hd, qt, b}.
__global__ __launch_bounds__(256) void attn_part_k(
    const ushort* __restrict__ qkv, float* __restrict__ Opart,
    float* __restrict__ lpart)
{
    // layout: K buf0 @0, K buf1 @4096, V buf0 @8192, V buf1 @12288
    __shared__ __align__(16) char smem[16384];

    int bid = blockIdx.x;
    int b    = bid & 7;
    int qt   = (bid >> 3) & 15;
    int hd   = (bid >> 7) & 3;
    int half = bid >> 9;
    int tid  = threadIdx.x;
    int wave = tid >> 6;
    int lane = tid & 63;
    int lg = lane >> 4, lr = lane & 15;

    const ushort* base = qkv + (size_t)b * LL * 384;
    int qr0 = qt * 128 + wave * 32;

    short8 qfA = *(const short8*)(base + (size_t)(qr0 + lr) * 384 + hd * 32 + lg * 8);
    short8 qfB = *(const short8*)(base + (size_t)(qr0 + 16 + lr) * 384 + hd * 32 + lg * 8);

    // ---- precomputed addresses ----
    int kk = tid >> 2, ks = tid & 3;
    int krow = kk & 31;
    int kchk = (((kk >> 5) << 2) + ks) ^ (krow & 7);
    int kwo = krow * 128 + (kchk << 4);
    const ushort* kptr = base + (size_t)(half * 1024 + kk) * 384 + 128 + hd * 32 + ks * 8;

    int k2 = (tid & 31) * 2, d0 = (tid >> 5) * 4;
    int rl = k2 & 31;
    int colp = (k2 >> 5) * 32 + ((rl >> 2) & 3) * 8 + (rl >> 4) * 4 + (rl & 3);
    int vchunk = colp >> 3;
    int vinb   = (colp * 2) & 15;
    int vwo0 = (d0+0)*128 + (((vchunk ^ ((d0+0)&7)) << 4) | vinb);
    int vwo1 = (d0+1)*128 + (((vchunk ^ ((d0+1)&7)) << 4) | vinb);
    int vwo2 = (d0+2)*128 + (((vchunk ^ ((d0+2)&7)) << 4) | vinb);
    int vwo3 = (d0+3)*128 + (((vchunk ^ ((d0+3)&7)) << 4) | vinb);
    const ushort* vptr = base + (size_t)(half * 1024 + k2) * 384 + 256 + hd * 32 + d0;

    int kro[4];
    #pragma unroll
    for (int n = 0; n < 4; ++n) {
        int r = ((n & 1) << 4) + lr;
        int c = (((n >> 1) << 2) + lg) ^ (r & 7);
        kro[n] = r * 128 + (c << 4);
    }
    int sx = (lg ^ (lr & 7)) << 4;
    int sy = ((4 + lg) ^ (lr & 7)) << 4;
    int vro0 = lr * 128 + sx;
    int vro1 = (16 + lr) * 128 + sx;
    int vro2 = lr * 128 + sy;
    int vro3 = (16 + lr) * 128 + sy;

    f32x4 OfA[2] = {}, OfB[2] = {};
    f32x4 OlA = {}, OlB = {};
    const f32x4 zero4 = {0.f, 0.f, 0.f, 0.f};
    short8 ones;
    #pragma unroll
    for (int e = 0; e < 8; ++e) ones[e] = (short)0x3F80;   // bf16 1.0

    const int TSTR = 64 * 384;
    const ushort* knext = kptr;
    const ushort* vnext = vptr;

    // prologue: tile 0 of this half
    {
        short8 kreg = *(const short8*)knext;
        uint2 va = *(const uint2*)vnext;
        uint2 vb = *(const uint2*)(vnext + 384);
        knext += TSTR; vnext += TSTR;
        *(short8*)(smem + 0 + kwo) = kreg;
        uint w0 = (va.x & 0xFFFFu) | (vb.x << 16);
        uint w1 = (va.x >> 16)     | (vb.x & 0xFFFF0000u);
        uint w2 = (va.y & 0xFFFFu) | (vb.y << 16);
        uint w3 = (va.y >> 16)     | (vb.y & 0xFFFF0000u);
        *(uint*)(smem + 8192 + vwo0) = w0;
        *(uint*)(smem + 8192 + vwo1) = w1;
        *(uint*)(smem + 8192 + vwo2) = w2;
        *(uint*)(smem + 8192 + vwo3) = w3;
    }
    __syncthreads();

#define ATTN_TILE(KRB, VRB, KWB, VWB, LAST) do {                              \
    short8 kreg_; uint2 va_, vb_;                                             \
    if (!(LAST)) {                                                            \
        kreg_ = *(const short8*)knext;                                        \
        va_   = *(const uint2*)vnext;                                         \
        vb_   = *(const uint2*)(vnext + 384);                                 \
        knext += TSTR; vnext += TSTR;                                         \
    }                                                                         \
    short8 kf0_ = *(const short8*)(smem + (KRB) + kro[0]);                    \
    short8 kf1_ = *(const short8*)(smem + (KRB) + kro[1]);                    \
    short8 kf2_ = *(const short8*)(smem + (KRB) + kro[2]);                    \
    short8 kf3_ = *(const short8*)(smem + (KRB) + kro[3]);                    \
    f32x4 SA0_ = __builtin_amdgcn_mfma_f32_16x16x32_bf16(kf0_, qfA, zero4,0,0,0); \
    f32x4 SA1_ = __builtin_amdgcn_mfma_f32_16x16x32_bf16(kf1_, qfA, zero4,0,0,0); \
    f32x4 SA2_ = __builtin_amdgcn_mfma_f32_16x16x32_bf16(kf2_, qfA, zero4,0,0,0); \
    f32x4 SA3_ = __builtin_amdgcn_mfma_f32_16x16x32_bf16(kf3_, qfA, zero4,0,0,0); \
    f32x4 SB0_ = __builtin_amdgcn_mfma_f32_16x16x32_bf16(kf0_, qfB, zero4,0,0,0); \
    f32x4 SB1_ = __builtin_amdgcn_mfma_f32_16x16x32_bf16(kf1_, qfB, zero4,0,0,0); \
    f32x4 SB2_ = __builtin_amdgcn_mfma_f32_16x16x32_bf16(kf2_, qfB, zero4,0,0,0); \
    f32x4 SB3_ = __builtin_amdgcn_mfma_f32_16x16x32_bf16(kf3_, qfB, zero4,0,0,0); \
    union { uint4 u; short8 s; } paA0_, paA1_, paB0_, paB1_;                  \
    paA0_.u.x = cvt_pk_bf16(fexp2(SA0_[0]), fexp2(SA0_[1]));                  \
    paA0_.u.y = cvt_pk_bf16(fexp2(SA0_[2]), fexp2(SA0_[3]));                  \
    paA0_.u.z = cvt_pk_bf16(fexp2(SA1_[0]), fexp2(SA1_[1]));                  \
    paA0_.u.w = cvt_pk_bf16(fexp2(SA1_[2]), fexp2(SA1_[3]));                  \
    paA1_.u.x = cvt_pk_bf16(fexp2(SA2_[0]), fexp2(SA2_[1]));                  \
    paA1_.u.y = cvt_pk_bf16(fexp2(SA2_[2]), fexp2(SA2_[3]));                  \
    paA1_.u.z = cvt_pk_bf16(fexp2(SA3_[0]), fexp2(SA3_[1]));                  \
    paA1_.u.w = cvt_pk_bf16(fexp2(SA3_[2]), fexp2(SA3_[3]));                  \
    paB0_.u.x = cvt_pk_bf16(fexp2(SB0_[0]), fexp2(SB0_[1]));                  \
    paB0_.u.y = cvt_pk_bf16(fexp2(SB0_[2]), fexp2(SB0_[3]));                  \
    paB0_.u.z = cvt_pk_bf16(fexp2(SB1_[0]), fexp2(SB1_[1]));                  \
    paB0_.u.w = cvt_pk_bf16(fexp2(SB1_[2]), fexp2(SB1_[3]));                  \
    paB1_.u.x = cvt_pk_bf16(fexp2(SB2_[0]), fexp2(SB2_[1]));                  \
    paB1_.u.y = cvt_pk_bf16(fexp2(SB2_[2]), fexp2(SB2_[3]));                  \
    paB1_.u.z = cvt_pk_bf16(fexp2(SB3_[0]), fexp2(SB3_[1]));                  \
    paB1_.u.w = cvt_pk_bf16(fexp2(SB3_[2]), fexp2(SB3_[3]));                  \
    short8 vb00_ = *(const short8*)(smem + (VRB) + vro0);                     \
    short8 vb01_ = *(const short8*)(smem + (VRB) + vro1);                     \
    short8 vb10_ = *(const short8*)(smem + (VRB) + vro2);                     \
    short8 vb11_ = *(const short8*)(smem + (VRB) + vro3);                     \
    OlA    = __builtin_amdgcn_mfma_f32_16x16x32_bf16(paA0_.s, ones,  OlA,   0,0,0); \
    OfA[0] = __builtin_amdgcn_mfma_f32_16x16x32_bf16(paA0_.s, vb00_, OfA[0],0,0,0); \
    OfA[1] = __builtin_amdgcn_mfma_f32_16x16x32_bf16(paA0_.s, vb01_, OfA[1],0,0,0); \
    OlA    = __builtin_amdgcn_mfma_f32_16x16x32_bf16(paA1_.s, ones,  OlA,   0,0,0); \
    OfA[0] = __builtin_amdgcn_mfma_f32_16x16x32_bf16(paA1_.s, vb10_, OfA[0],0,0,0); \
    OfA[1] = __builtin_amdgcn_mfma_f32_16x16x32_bf16(paA1_.s, vb11_, OfA[1],0,0,0); \
    OlB    = __builtin_amdgcn_mfma_f32_16x16x32_bf16(paB0_.s, ones,  OlB,   0,0,0); \
    OfB[0] = __builtin_amdgcn_mfma_f32_16x16x32_bf16(paB0_.s, vb00_, OfB[0],0,0,0); \
    OfB[1] = __builtin_amdgcn_mfma_f32_16x16x32_bf16(paB0_.s, vb01_, OfB[1],0,0,0); \
    OlB    = __builtin_amdgcn_mfma_f32_16x16x32_bf16(paB1_.s, ones,  OlB,   0,0,0); \
    OfB[0] = __builtin_amdgcn_mfma_f32_16x16x32_bf16(paB1_.s, vb10_, OfB[0],0,0,0); \
    OfB[1] = __builtin_amdgcn_mfma_f32_16x16x32_bf16(paB1_.s, vb11_, OfB[1],0,0,0); \
    if (!(LAST)) {                                                            \
        *(short8*)(smem + (KWB) + kwo) = kreg_;                               \
        uint w0_ = (va_.x & 0xFFFFu) | (vb_.x << 16);                         \
        uint w1_ = (va_.x >> 16)     | (vb_.x & 0xFFFF0000u);                 \
        uint w2_ = (va_.y & 0xFFFFu) | (vb_.y << 16);                         \
        uint w3_ = (va_.y >> 16)     | (vb_.y & 0xFFFF0000u);                 \
        *(uint*)(smem + (VWB) + vwo0) = w0_;                                  \
        *(uint*)(smem + (VWB) + vwo1) = w1_;                                  \
        *(uint*)(smem + (VWB) + vwo2) = w2_;                                  \
        *(uint*)(smem + (VWB) + vwo3) = w3_;                                  \
    }                                                                         \
    __syncthreads();                                                          \
} while (0)

    #pragma unroll 1
    for (int t = 0; t < 16; t += 2) {
        ATTN_TILE(0,    8192,  4096, 12288, false);
        ATTN_TILE(4096, 12288, 0,    8192,  (t + 2 >= 16));
    }
#undef ATTN_TILE

    // write fp32 partials: Opart[bid][q_local(128)][d_local(32)], lpart[bid][q_local]
    #pragma unroll
    for (int j = 0; j < 4; ++j) {
        int qa = wave * 32 + lg * 4 + j;
        size_t oa = ((size_t)bid * 128 + qa) * 32;
        Opart[oa + lr]      = OfA[0][j];
        Opart[oa + 16 + lr] = OfA[1][j];
        if (lr == 0) lpart[(size_t)bid * 128 + qa] = OlA[j];
        int qb = qa + 16;
        size_t ob = ((size_t)bid * 128 + qb) * 32;
        Opart[ob + lr]      = OfB[0][j];
        Opart[ob + 16 + lr] = OfB[1][j];
        if (lr == 0) lpart[(size_t)bid * 128 + qb] = OlB[j];
    }
}

// ---------------- attention merge: o = (O0+O1)/(l0+l1), bf16 out ----------------
__global__ __launch_bounds__(256) void attn_merge_k(
    const float* __restrict__ Opart, const float* __restrict__ lpart,
    ushort* __restrict__ o)
{
    int i = blockIdx.x * 256 + threadIdx.x;   // over BLROWS*64 (2 elems/thread)
    int d2  = (i & 63) * 2;
    int row = i >> 6;                          // b*2048 + q
    int b = row >> 11, q = row & 2047;
    int hd = d2 >> 5, dl = d2 & 31;
    int qt = q >> 7, ql = q & 127;
    int bid0 = (hd << 7) | (qt << 3) | b;
    int bid1 = bid0 + 512;
    size_t p0 = ((size_t)bid0 * 128 + ql) * 32 + dl;
    size_t p1 = ((size_t)bid1 * 128 + ql) * 32 + dl;
    float2 a = *(const float2*)(Opart + p0);
    float2 c = *(const float2*)(Opart + p1);
    float l = lpart[(size_t)bid0 * 128 + ql] + lpart[(size_t)bid1 * 128 + ql];
    float inv = 1.f / l;
    unsigned pw = cvt_pk_bf16((a.x + c.x) * inv, (a.y + c.y) * inv);
    *(unsigned*)(o + (size_t)row * 128 + d2) = pw;
}

// ---------------- x_proj bf16 MFMA: dbc[M,40] = xm[M,256] @ W[40,256]^T ----------------
__global__ __launch_bounds__(256) void xproj_bf16_k(
    const float* __restrict__ A, const ushort* __restrict__ W16,
    float* __restrict__ C)
{
    __shared__ __align__(16) short As[64][264];
    __shared__ __align__(16) short Ws[48][264];
    int tid = threadIdx.x;
    int w = tid >> 6, lane = tid & 63, lg = lane >> 4, lr = lane & 15;
    int row0 = blockIdx.x * 64;

    const float* Ab = A + (size_t)row0 * 256;
    #pragma unroll
    for (int p = 0; p < 16; ++p) {
        int off = p * 1024 + tid * 4;
        float4 v = *(const float4*)(Ab + off);
        uint2 pw; pw.x = cvt_pk_bf16(v.x, v.y); pw.y = cvt_pk_bf16(v.z, v.w);
        *(uint2*)&As[off >> 8][off & 255] = pw;
    }
    #pragma unroll
    for (int p = 0; p < 6; ++p) {
        int off = p * 2048 + tid * 8;
        int r = off >> 8, c = off & 255;
        short8 v = {};
        if (r < 40) v = *(const short8*)(W16 + (size_t)r * 256 + c);
        *(short8*)&Ws[r][c] = v;
    }
    __syncthreads();

    short8 af[8];
    #pragma unroll
    for (int kk = 0; kk < 8; ++kk)
        af[kk] = *(short8*)&As[w * 16 + lr][kk * 32 + lg * 8];

    f32x4 acc[3];
    #pragma unroll
    for (int n = 0; n < 3; ++n) acc[n] = (f32x4){0.f, 0.f, 0.f, 0.f};
    #pragma unroll
    for (int n = 0; n < 3; ++n)
        #pragma unroll
        for (int kk = 0; kk < 8; ++kk) {
            short8 bf = *(short8*)&Ws[n * 16 + lr][kk * 32 + lg * 8];
            acc[n] = __builtin_amdgcn_mfma_f32_16x16x32_bf16(af[kk], bf, acc[n], 0, 0, 0);
        }
    #pragma unroll
    for (int n = 0; n < 3; ++n) {
        int col = n * 16 + lr;
        if (col < 40) {
            #pragma unroll
            for (int j = 0; j < 4; ++j) {
                int row = row0 + w * 16 + lg * 4 + j;
                C[(size_t)row * 40 + col] = acc[n][j];
            }
        }
    }
}

// ---------------- causal depthwise conv(4) + silu ----------------
__global__ __launch_bounds__(256) void conv_silu_k(
    const float* __restrict__ xz, const float* __restrict__ cw,
    const float* __restrict__ cb, float* __restrict__ xm)
{
    int idx = blockIdx.x * 256 + threadIdx.x;
    int d   = idx & 255;
    int row = idx >> 8;
    int l   = row & (LL - 1);
    float a = cb[d];
    #pragma unroll
    for (int t = 0; t < 4; ++t) {
        int ll = l - 3 + t;
        if (ll >= 0) a += cw[d * 4 + t] * xz[(size_t)(row - 3 + t) * 512 + d];
    }
    float sg = 1.f / (1.f + expf(-a));
    xm[idx] = a * sg;
}

// ---------------- dt = softplus(dbc[:, :8] @ dt_w^T + dt_b), 4 rows/block ----------------
__global__ __launch_bounds__(256) void dtproj_k(
    const float* __restrict__ dbc, const float* __restrict__ w,
    const float* __restrict__ bias, float* __restrict__ dt)
{
    int row0 = blockIdx.x * 4, n = threadIdx.x;
    __shared__ float dv[4][8];
    if (n < 32) dv[n >> 3][n & 7] = dbc[(size_t)(row0 + (n >> 3)) * 40 + (n & 7)];
    __syncthreads();
    float bv = bias[n];
    float wv[8];
    #pragma unroll
    for (int k = 0; k < 8; ++k) wv[k] = w[n * 8 + k];
    #pragma unroll
    for (int r = 0; r < 4; ++r) {
        float a = bv;
        #pragma unroll
        for (int k = 0; k < 8; ++k) a += dv[r][k] * wv[k];
        float sp = fmaxf(a, 0.f) + log1pf(expf(-fabsf(a)));
        dt[(size_t)(row0 + r) * 256 + n] = sp;
    }
}

// ---------------- scan pass 1: thread=(d, sh), 8 states; coalesced loads ----------------
__global__ __launch_bounds__(512) void scan1_k(
    const float* __restrict__ dt, const float* __restrict__ xm,
    const float* __restrict__ dbc, const float* __restrict__ A_log,
    float* __restrict__ Asum, float* __restrict__ Bsum)
{
    int blk = blockIdx.x;             // b*32 + c
    int c = blk & 31, b = blk >> 5;
    int tid = threadIdx.x;
    int d = tid >> 1, sh = tid & 1;
    float Av2[8];
    {
        float4 a0 = *(const float4*)(A_log + d * 16 + sh * 8);
        float4 a1 = *(const float4*)(A_log + d * 16 + sh * 8 + 4);
        Av2[0] = -expf(a0.x) * 1.4426950408889634f;
        Av2[1] = -expf(a0.y) * 1.4426950408889634f;
        Av2[2] = -expf(a0.z) * 1.4426950408889634f;
        Av2[3] = -expf(a0.w) * 1.4426950408889634f;
        Av2[4] = -expf(a1.x) * 1.4426950408889634f;
        Av2[5] = -expf(a1.y) * 1.4426950408889634f;
        Av2[6] = -expf(a1.z) * 1.4426950408889634f;
        Av2[7] = -expf(a1.w) * 1.4426950408889634f;
    }
    float aarg[8] = {}, Bacc[8] = {};
    __shared__ float Bst[CH][16];
    size_t rowb = (size_t)b * LL + c * CH;
    {
        int e = tid * 2;
        int j = e >> 4, col = e & 15;
        float2 v = *(const float2*)(dbc + (rowb + j) * 40 + 8 + col);
        Bst[j][col] = v.x; Bst[j][col + 1] = v.y;
    }
    __syncthreads();
    #pragma unroll 4
    for (int j = 0; j < CH; ++j) {
        size_t rr = rowb + j;
        float dtv = dt[rr * 256 + d];
        float xmv = xm[rr * 256 + d];
        float dtxm = dtv * xmv;
        float4 b0 = *(const float4*)&Bst[j][sh * 8];
        float4 b1 = *(const float4*)&Bst[j][sh * 8 + 4];
        float bb[8] = {b0.x, b0.y, b0.z, b0.w, b1.x, b1.y, b1.z, b1.w};
        #pragma unroll
        for (int k = 0; k < 8; ++k) {
            float arg = dtv * Av2[k];
            Bacc[k] = Bacc[k] * fexp2(arg) + bb[k] * dtxm;
            aarg[k] += arg;
        }
    }
    #pragma unroll
    for (int k = 0; k < 8; ++k) {
        size_t oo = ((size_t)(blk * 16 + sh * 8 + k)) * 256 + d;
        Asum[oo] = fexp2(aarg[k]);
        Bsum[oo] = Bacc[k];
    }
}

// ---------------- scan mid ----------------
__global__ __launch_bounds__(256) void scan_mid_k(
    const float* __restrict__ Asum, const float* __restrict__ Bsum,
    float* __restrict__ hinit)
{
    int b = blockIdx.x >> 4, s = blockIdx.x & 15;
    int d = threadIdx.x;
    float h = 0.f;
    #pragma unroll 4
    for (int c = 0; c < NCHUNK; ++c) {
        size_t oo = ((size_t)((b * 32 + c) * 16 + s)) * 256 + d;
        hinit[oo] = h;
        h = Asum[oo] * h + Bsum[oo];
    }
}

// ---------------- scan pass 2 + gate + pool: thread=(d, sh), 8 states ----------------
__global__ __launch_bounds__(512) void scan2_k(
    const float* __restrict__ dt, const float* __restrict__ xm,
    const float* __restrict__ dbc, const float* __restrict__ A_log,
    const float* __restrict__ hinit, const float* __restrict__ xz,
    const float* __restrict__ dsk, float* __restrict__ part)
{
    int blk = blockIdx.x;
    int c = blk & 31, b = blk >> 5;
    int tid = threadIdx.x;
    int d = tid >> 1, sh = tid & 1;
    float Av2[8];
    {
        float4 a0 = *(const float4*)(A_log + d * 16 + sh * 8);
        float4 a1 = *(const float4*)(A_log + d * 16 + sh * 8 + 4);
        Av2[0] = -expf(a0.x) * 1.4426950408889634f;
        Av2[1] = -expf(a0.y) * 1.4426950408889634f;
        Av2[2] = -expf(a0.z) * 1.4426950408889634f;
        Av2[3] = -expf(a0.w) * 1.4426950408889634f;
        Av2[4] = -expf(a1.x) * 1.4426950408889634f;
        Av2[5] = -expf(a1.y) * 1.4426950408889634f;
        Av2[6] = -expf(a1.z) * 1.4426950408889634f;
        Av2[7] = -expf(a1.w) * 1.4426950408889634f;
    }
    float hs[8];
    #pragma unroll
    for (int k = 0; k < 8; ++k)
        hs[k] = hinit[((size_t)(blk * 16 + sh * 8 + k)) * 256 + d];
    float dskv = dsk[d];
    float psum = 0.f;
    __shared__ float Bst[CH][16], Cst[CH][16];
    size_t rowb = (size_t)b * LL + c * CH;
    {
        int e = tid * 2;
        int j = e >> 4, col = e & 15;
        float2 v = *(const float2*)(dbc + (rowb + j) * 40 + 8 + col);
        Bst[j][col] = v.x; Bst[j][col + 1] = v.y;
        float2 u = *(const float2*)(dbc + (rowb + j) * 40 + 24 + col);
        Cst[j][col] = u.x; Cst[j][col + 1] = u.y;
    }
    __syncthreads();
    #pragma unroll 2
    for (int j = 0; j < CH; ++j) {
        size_t rr = rowb + j;
        float dtv = dt[rr * 256 + d];
        float xmv = xm[rr * 256 + d];
        float dtxm = dtv * xmv;
        float4 b0 = *(const float4*)&Bst[j][sh * 8];
        float4 b1 = *(const float4*)&Bst[j][sh * 8 + 4];
        float4 c0 = *(const float4*)&Cst[j][sh * 8];
        float4 c1 = *(const float4*)&Cst[j][sh * 8 + 4];
        float bb[8] = {b0.x, b0.y, b0.z, b0.w, b1.x, b1.y, b1.z, b1.w};
        float cc[8] = {c0.x, c0.y, c0.z, c0.w, c1.x, c1.y, c1.z, c1.w};
        float yv = 0.f;
        #pragma unroll
        for (int k = 0; k < 8; ++k) {
            float dA = fexp2(dtv * Av2[k]);
            hs[k] = hs[k] * dA + bb[k] * dtxm;
            yv += hs[k] * cc[k];
        }
        yv += __shfl_xor(yv, 1);
        float zv = xz[rr * 512 + 256 + d];
        float sg = zv / (1.f + __expf(-zv));
        psum += (yv + xmv * dskv) * sg;
    }
    if (sh == 0) part[(size_t)blk * 256 + d] = psum;   // part[b][c][d]
}

// ---------------- final: pooled @ out_proj^T -> mlp2 ----------------
__global__ __launch_bounds__(128) void final_k(
    const float* __restrict__ part, const float* __restrict__ opw,
    const float* __restrict__ w1, const float* __restrict__ b1,
    const float* __restrict__ w2, const float* __restrict__ b2,
    float* __restrict__ out)
{
    int b = blockIdx.x, t = threadIdx.x;
    __shared__ float pg[256];
    __shared__ float pooled[128];
    __shared__ float hid[32];
    for (int k = t; k < 256; k += 128) {
        float sm = 0.f;
        #pragma unroll
        for (int c = 0; c < NCHUNK; ++c)
            sm += part[(size_t)(b * 32 + c) * 256 + k];
        pg[k] = sm * (1.f / 2048.f);
    }
    __syncthreads();
    float a = 0.f;
    for (int k = 0; k < 256; ++k) a += pg[k] * opw[(size_t)t * DIN + k];
    pooled[t] = a;
    __syncthreads();
    if (t < 32) {
        float hh = b1[t];
        for (int d2 = 0; d2 < 128; ++d2) hh += pooled[d2] * w1[t * 128 + d2];
        hid[t] = fmaxf(hh, 0.f);
    }
    __syncthreads();
    if (t == 0) {
        float o = b2[0];
        #pragma unroll
        for (int j = 0; j < 32; ++j) o += hid[j] * w2[j];
        out[b] = o;
    }
}

extern "C" void kernel_launch(void* const* d_in, const int* in_sizes, int n_in,
                              void* d_out, int out_size, void* d_ws, size_t ws_size,
                              hipStream_t stream)
{
    const float* x          = (const float*)d_in[0];
    const float* mlp1_w     = (const float*)d_in[1];
    const float* mlp1_b     = (const float*)d_in[2];
    const float* qkv_w      = (const float*)d_in[3];
    const float* qkv_b      = (const float*)d_in[4];
    const float* attn_out_w = (const float*)d_in[5];
    const float* attn_out_b = (const float*)d_in[6];
    const float* ln1_s      = (const float*)d_in[7];
    const float* ln1_b      = (const float*)d_in[8];
    const float* ffw_w1     = (const float*)d_in[9];
    const float* ffw_b1     = (const float*)d_in[10];
    const float* ffw_w2     = (const float*)d_in[11];
    const float* ffw_b2     = (const float*)d_in[12];
    const float* ln2_s      = (const float*)d_in[13];
    const float* ln2_b      = (const float*)d_in[14];
    const float* in_proj_w  = (const float*)d_in[15];
    const float* conv_w     = (const float*)d_in[16];
    const float* conv_b     = (const float*)d_in[17];
    const float* x_proj_w   = (const float*)d_in[18];
    const float* dt_proj_w  = (const float*)d_in[19];
    const float* dt_proj_b  = (const float*)d_in[20];
    const float* A_log      = (const float*)d_in[21];
    const float* D_skip     = (const float*)d_in[22];
    const float* out_proj_w = (const float*)d_in[23];
    const float* mlp2_w1    = (const float*)d_in[24];
    const float* mlp2_b1    = (const float*)d_in[25];
    const float* mlp2_w2    = (const float*)d_in[26];
    const float* mlp2_b2    = (const float*)d_in[27];
    float* out = (float*)d_out;
    float* ws  = (float*)d_ws;

    // workspace layout (floats)
    float* h     = ws;                              // BLROWS*128
    float* xz    = h    + (size_t)BLROWS * DMODEL;  // BLROWS*512  (qkv16 alias)
    float* t1    = xz   + (size_t)BLROWS * 512;     // BLROWS*128 (attn-out bf16 alias / dt)
    float* t2    = t1   + (size_t)BLROWS * DMODEL;  // BLROWS*128
    float* xm    = t2   + (size_t)BLROWS * DMODEL;  // BLROWS*256 (attn Opart in layers phase)
    float* dbc   = xm   + (size_t)BLROWS * DIN;     // BLROWS*40  (attn lpart in layers phase)
    float* part2 = dbc  + (size_t)BLROWS * 40;      // 8*32*256
    float* Asum  = part2 + 8 * 32 * 256;            // 8*32*16*256
    float* Bsum  = Asum + 8 * 32 * 16 * 256;
    float* hini  = Bsum + 8 * 32 * 16 * 256;
    ushort* w16  = (ushort*)(hini + 8 * 32 * 16 * 256);
    ushort* qkvw16 = w16;                 // 6*384*128 = 294912
    ushort* aow16  = w16 + 294912;        // 98304
    ushort* f1w16  = w16 + 393216;        // 98304
    ushort* f2w16  = w16 + 491520;        // 98304
    ushort* ipw16  = w16 + 589824;        // 65536
    ushort* xpw16  = w16 + 655360;        // 10240
    ushort* qkv16 = (ushort*)xz;
    ushort* t1u   = (ushort*)t1;          // attn out bf16
    float* dtb  = t1;                     // dt (fp32) in mamba phase
    float* Oprt = xm;                     // 1024*128*32 = 4.19M floats (layers phase)
    float* lprt = dbc;                    // 1024*128 floats (layers phase)
    (void)t2;

    // weight preconversion
    wcvt_k<<<(294912/4 + 255)/256, 256, 0, stream>>>(qkv_w, qkvw16, 294912/4);
    wcvt_k<<<(98304/4 + 255)/256, 256, 0, stream>>>(attn_out_w, aow16, 98304/4);
    wcvt_k<<<(98304/4 + 255)/256, 256, 0, stream>>>(ffw_w1, f1w16, 98304/4);
    wcvt_k<<<(98304/4 + 255)/256, 256, 0, stream>>>(ffw_w2, f2w16, 98304/4);
    wcvt_k<<<(65536/4 + 255)/256, 256, 0, stream>>>(in_proj_w, ipw16, 65536/4);
    wcvt_k<<<(10240/4 + 255)/256, 256, 0, stream>>>(x_proj_w, xpw16, 10240/4);

    mlp1_pe_k<<<(BLROWS * DMODEL) / 256, 256, 0, stream>>>(x, mlp1_w, mlp1_b, h);

    for (int i = 0; i < NLAYERS; ++i) {
        gemm_qkv_k<<<dim3(3, 256), 256, 0, stream>>>(
            h, qkvw16 + (size_t)i * 384 * 128, qkv_b + i * 384, qkv16);
        attn_part_k<<<1024, 256, 0, stream>>>(qkv16, Oprt, lprt);
        attn_merge_k<<<(BLROWS * 64) / 256, 256, 0, stream>>>(Oprt, lprt, t1u);
        gemm_ln_k<<<256, 256, 0, stream>>>(
            t1u, aow16 + (size_t)i * 128 * 128, attn_out_b + i * 128, h,
            ln1_s + i * 128, ln1_b + i * 128);
        ffw_ln_k<<<256, 256, 0, stream>>>(
            h, f1w16 + (size_t)i * 128 * 128, ffw_b1 + i * 128,
            f2w16 + (size_t)i * 128 * 128, ffw_b2 + i * 128,
            ln2_s + i * 128, ln2_b + i * 128);
    }

    // Mamba block
    gemm_bf16_k<<<dim3(4, 256), 256, 0, stream>>>(h, ipw16, xz, 512);
    conv_silu_k<<<(BLROWS * DIN) / 256, 256, 0, stream>>>(xz, conv_w, conv_b, xm);
    xproj_bf16_k<<<256, 256, 0, stream>>>(xm, xpw16, dbc);
    dtproj_k<<<BLROWS / 4, 256, 0, stream>>>(dbc, dt_proj_w, dt_proj_b, dtb);
    scan1_k<<<256, 512, 0, stream>>>(dtb, xm, dbc, A_log, Asum, Bsum);
    scan_mid_k<<<128, 256, 0, stream>>>(Asum, Bsum, hini);
    scan2_k<<<256, 512, 0, stream>>>(dtb, xm, dbc, A_log, hini, xz, D_skip, part2);
    final_k<<<8, 128, 0, stream>>>(part2, out_proj_w, mlp2_w1, mlp2_b1, mlp2_w2, mlp2_b2, out);
}

// Round 15
// 459.704 us; speedup vs baseline: 1.0454x; 1.0454x over previous
//
#include <hip/hip_runtime.h>
#include <math.h>

#define BB 8
#define LL 2048
#define DMODEL 128
#define NHEAD 4
#define DHEAD 32
#define DIN 256
#define DSTATE 16
#define NLAYERS 6
#define BLROWS (BB*LL)   // 16384
#define NCHUNK 32
#define CH 64            // scan chunk length

typedef __attribute__((ext_vector_type(8))) short short8;
typedef __attribute__((ext_vector_type(4))) float f32x4;

static __device__ __forceinline__ unsigned cvt_pk_bf16(float a, float b) {
    unsigned r;
    asm volatile("v_cvt_pk_bf16_f32 %0, %1, %2" : "=v"(r) : "v"(a), "v"(b));
    return r;
}
// raw v_exp_f32 (2^x): 1 instruction; args bounded -> OCML clamp is overhead.
static __device__ __forceinline__ float fexp2(float x) {
    float r;
    asm("v_exp_f32 %0, %1" : "=v"(r) : "v"(x));
    return r;
}

// ---------------- weight fp32 -> bf16 preconversion ----------------
__global__ __launch_bounds__(256) void wcvt_k(
    const float* __restrict__ src, ushort* __restrict__ dst, int n4)
{
    int i = blockIdx.x * 256 + threadIdx.x;
    if (i < n4) {
        float4 v = ((const float4*)src)[i];
        uint2 pw; pw.x = cvt_pk_bf16(v.x, v.y); pw.y = cvt_pk_bf16(v.z, v.w);
        ((uint2*)dst)[i] = pw;
    }
}

// ---------------- mlp1 + positional encoding ----------------
__global__ __launch_bounds__(256) void mlp1_pe_k(
    const float* __restrict__ x, const float* __restrict__ w,
    const float* __restrict__ b, float* __restrict__ h)
{
    int idx = blockIdx.x * 256 + threadIdx.x;   // over BLROWS*128
    int d   = idx & 127;
    int row = idx >> 7;
    int pos = row & (LL - 1);
    float v = x[row] * w[d] + b[d];
    int j2 = (d >> 1) * 2;
    float dv = expf((float)j2 * -0.07195578415603638f);
    float ang = (float)pos * dv;
    v += (d & 1) ? cosf(ang) : sinf(ang);
    h[idx] = v;
}

// ---------------- qkv GEMM: bf16 out, q pre-scaled; V written PAIRED to vbuf ----------------
#define QSCALE (0.17677669529663687f * 1.4426950408889634f)   // 1/sqrt(32) * log2(e)
__global__ __launch_bounds__(256) void gemm_qkv_k(
    const float* __restrict__ A, const ushort* __restrict__ W16,
    const float* __restrict__ bias, ushort* __restrict__ C16,
    unsigned* __restrict__ vbuf)
{
    __shared__ __align__(16) short As[64][136];
    __shared__ __align__(16) short Ws[128][136];
    int tid = threadIdx.x;
    int w = tid >> 6, lane = tid & 63, lg = lane >> 4, lr = lane & 15;
    int row0 = blockIdx.y * 64, col0 = blockIdx.x * 128;

    const float* Ab = A + (size_t)row0 * 128;
    #pragma unroll
    for (int p = 0; p < 8; ++p) {
        int off = p * 1024 + tid * 4;
        float4 v = *(const float4*)(Ab + off);
        uint2 pw; pw.x = cvt_pk_bf16(v.x, v.y); pw.y = cvt_pk_bf16(v.z, v.w);
        *(uint2*)&As[off >> 7][off & 127] = pw;
    }
    const ushort* Wb = W16 + (size_t)col0 * 128;
    #pragma unroll
    for (int p = 0; p < 8; ++p) {
        int off = p * 2048 + tid * 8;
        short8 v = *(const short8*)(Wb + off);
        *(short8*)&Ws[off >> 7][off & 127] = v;
    }
    __syncthreads();

    short8 af[4];
    #pragma unroll
    for (int kk = 0; kk < 4; ++kk)
        af[kk] = *(short8*)&As[w * 16 + lr][kk * 32 + lg * 8];
    f32x4 acc[8];
    #pragma unroll
    for (int n = 0; n < 8; ++n) acc[n] = (f32x4){0.f, 0.f, 0.f, 0.f};
    #pragma unroll
    for (int n = 0; n < 8; ++n)
        #pragma unroll
        for (int kk = 0; kk < 4; ++kk) {
            short8 bf = *(short8*)&Ws[n * 16 + lr][kk * 32 + lg * 8];
            acc[n] = __builtin_amdgcn_mfma_f32_16x16x32_bf16(af[kk], bf, acc[n], 0, 0, 0);
        }

    if (blockIdx.x == 2) {
        // V block: write key-paired bf16 words {V[2l][d], V[2l+1][d]} to vbuf
        #pragma unroll
        for (int n = 0; n < 8; ++n) {
            int dfull = n * 16 + lr;
            int hd2 = dfull >> 5, dl = dfull & 31;
            float bv = bias[256 + dfull];
            #pragma unroll
            for (int p = 0; p < 2; ++p) {
                int row = row0 + w * 16 + lg * 4 + p * 2;   // even l
                int bb2 = row >> 11, l = row & 2047;
                unsigned pw = cvt_pk_bf16(acc[n][p * 2] + bv, acc[n][p * 2 + 1] + bv);
                vbuf[(((size_t)bb2 * 4 + hd2) * 1024 + (l >> 1)) * 32 + dl] = pw;
            }
        }
    } else {
        float qs = (blockIdx.x == 0) ? QSCALE : 1.f;
        #pragma unroll
        for (int n = 0; n < 8; ++n) {
            int col = col0 + n * 16 + lr;
            float bv = bias[col];
            #pragma unroll
            for (int j = 0; j < 4; ++j) {
                int row = row0 + w * 16 + lg * 4 + j;
                float v = (acc[n][j] + bv) * qs;
                C16[(size_t)row * 384 + col] = (ushort)cvt_pk_bf16(v, v);
            }
        }
    }
}

// ---------------- bf16 MFMA GEMM (in_proj): C[M,N] = A[M,128] @ W[N,128]^T ----------------
__global__ __launch_bounds__(256) void gemm_bf16_k(
    const float* __restrict__ A, const ushort* __restrict__ W16,
    float* __restrict__ C, int N)
{
    __shared__ __align__(16) short As[64][136];
    __shared__ __align__(16) short Ws[128][136];
    int tid = threadIdx.x;
    int w = tid >> 6, lane = tid & 63, lg = lane >> 4, lr = lane & 15;
    int row0 = blockIdx.y * 64, col0 = blockIdx.x * 128;

    const float* Ab = A + (size_t)row0 * 128;
    #pragma unroll
    for (int p = 0; p < 8; ++p) {
        int off = p * 1024 + tid * 4;
        float4 v = *(const float4*)(Ab + off);
        uint2 pw; pw.x = cvt_pk_bf16(v.x, v.y); pw.y = cvt_pk_bf16(v.z, v.w);
        *(uint2*)&As[off >> 7][off & 127] = pw;
    }
    const ushort* Wb = W16 + (size_t)col0 * 128;
    #pragma unroll
    for (int p = 0; p < 8; ++p) {
        int off = p * 2048 + tid * 8;
        short8 v = *(const short8*)(Wb + off);
        *(short8*)&Ws[off >> 7][off & 127] = v;
    }
    __syncthreads();

    short8 af[4];
    #pragma unroll
    for (int kk = 0; kk < 4; ++kk)
        af[kk] = *(short8*)&As[w * 16 + lr][kk * 32 + lg * 8];
    f32x4 acc[8];
    #pragma unroll
    for (int n = 0; n < 8; ++n) acc[n] = (f32x4){0.f, 0.f, 0.f, 0.f};
    #pragma unroll
    for (int n = 0; n < 8; ++n)
        #pragma unroll
        for (int kk = 0; kk < 4; ++kk) {
            short8 bf = *(short8*)&Ws[n * 16 + lr][kk * 32 + lg * 8];
            acc[n] = __builtin_amdgcn_mfma_f32_16x16x32_bf16(af[kk], bf, acc[n], 0, 0, 0);
        }
    #pragma unroll
    for (int n = 0; n < 8; ++n) {
        int col = col0 + n * 16 + lr;
        #pragma unroll
        for (int j = 0; j < 4; ++j) {
            int row = row0 + w * 16 + lg * 4 + j;
            C[(size_t)row * N + col] = acc[n][j];
        }
    }
}

// ---------------- fused GEMM(N=128) + residual + LayerNorm (A bf16, W bf16) ----------------
__global__ __launch_bounds__(256) void gemm_ln_k(
    const ushort* __restrict__ A16, const ushort* __restrict__ W16,
    const float* __restrict__ bias, float* __restrict__ h,
    const float* __restrict__ ls, const float* __restrict__ lb)
{
    __shared__ __align__(16) short As[64][136];
    __shared__ __align__(16) short Ws[128][136];
    int tid = threadIdx.x;
    int w = tid >> 6, lane = tid & 63, lg = lane >> 4, lr = lane & 15;
    int row0 = blockIdx.x * 64;

    const ushort* Ab = A16 + (size_t)row0 * 128;
    #pragma unroll
    for (int p = 0; p < 4; ++p) {
        int off = p * 2048 + tid * 8;
        short8 v = *(const short8*)(Ab + off);
        *(short8*)&As[off >> 7][off & 127] = v;
    }
    #pragma unroll
    for (int p = 0; p < 8; ++p) {
        int off = p * 2048 + tid * 8;
        short8 v = *(const short8*)(W16 + off);
        *(short8*)&Ws[off >> 7][off & 127] = v;
    }
    __syncthreads();

    short8 af[4];
    #pragma unroll
    for (int kk = 0; kk < 4; ++kk)
        af[kk] = *(short8*)&As[w * 16 + lr][kk * 32 + lg * 8];
    f32x4 acc[8];
    #pragma unroll
    for (int n = 0; n < 8; ++n) acc[n] = (f32x4){0.f, 0.f, 0.f, 0.f};
    #pragma unroll
    for (int n = 0; n < 8; ++n)
        #pragma unroll
        for (int kk = 0; kk < 4; ++kk) {
            short8 bf = *(short8*)&Ws[n * 16 + lr][kk * 32 + lg * 8];
            acc[n] = __builtin_amdgcn_mfma_f32_16x16x32_bf16(af[kk], bf, acc[n], 0, 0, 0);
        }

    float bv[8], lsv[8], lbv[8];
    #pragma unroll
    for (int n = 0; n < 8; ++n) {
        int col = n * 16 + lr;
        bv[n] = bias[col]; lsv[n] = ls[col]; lbv[n] = lb[col];
    }
    #pragma unroll
    for (int j = 0; j < 4; ++j) {
        int row = row0 + w * 16 + lg * 4 + j;
        float xv[8]; float sum = 0.f;
        #pragma unroll
        for (int n = 0; n < 8; ++n) {
            xv[n] = acc[n][j] + bv[n] + h[(size_t)row * 128 + n * 16 + lr];
            sum += xv[n];
        }
        sum += __shfl_xor(sum, 1); sum += __shfl_xor(sum, 2);
        sum += __shfl_xor(sum, 4); sum += __shfl_xor(sum, 8);
        float mean = sum * (1.f / 128.f);
        float vs = 0.f;
        #pragma unroll
        for (int n = 0; n < 8; ++n) { float dd = xv[n] - mean; vs += dd * dd; }
        vs += __shfl_xor(vs, 1); vs += __shfl_xor(vs, 2);
        vs += __shfl_xor(vs, 4); vs += __shfl_xor(vs, 8);
        float inv = rsqrtf(vs * (1.f / 128.f) + 1e-5f);
        #pragma unroll
        for (int n = 0; n < 8; ++n)
            h[(size_t)row * 128 + n * 16 + lr] = (xv[n] - mean) * inv * lsv[n] + lbv[n];
    }
}

// ---------------- fused FFW (w1+relu+w2) + residual + LayerNorm (W bf16) ----------------
__global__ __launch_bounds__(256) void ffw_ln_k(
    float* __restrict__ h, const ushort* __restrict__ W1, const float* __restrict__ b1,
    const ushort* __restrict__ W2, const float* __restrict__ b2,
    const float* __restrict__ ls, const float* __restrict__ lb)
{
    __shared__ __align__(16) short As[64][136];
    __shared__ __align__(16) short Ws[128][136];
    int tid = threadIdx.x;
    int w = tid >> 6, lane = tid & 63, lg = lane >> 4, lr = lane & 15;
    int row0 = blockIdx.x * 64;

    const float* Ab = h + (size_t)row0 * 128;
    #pragma unroll
    for (int p = 0; p < 8; ++p) {
        int off = p * 1024 + tid * 4;
        float4 v = *(const float4*)(Ab + off);
        uint2 pw; pw.x = cvt_pk_bf16(v.x, v.y); pw.y = cvt_pk_bf16(v.z, v.w);
        *(uint2*)&As[off >> 7][off & 127] = pw;
    }
    #pragma unroll
    for (int p = 0; p < 8; ++p) {
        int off = p * 2048 + tid * 8;
        short8 v = *(const short8*)(W1 + off);
        *(short8*)&Ws[off >> 7][off & 127] = v;
    }
    __syncthreads();

    short8 af[4];
    #pragma unroll
    for (int kk = 0; kk < 4; ++kk)
        af[kk] = *(short8*)&As[w * 16 + lr][kk * 32 + lg * 8];
    f32x4 acc[8];
    #pragma unroll
    for (int n = 0; n < 8; ++n) acc[n] = (f32x4){0.f, 0.f, 0.f, 0.f};
    #pragma unroll
    for (int n = 0; n < 8; ++n)
        #pragma unroll
        for (int kk = 0; kk < 4; ++kk) {
            short8 bf = *(short8*)&Ws[n * 16 + lr][kk * 32 + lg * 8];
            acc[n] = __builtin_amdgcn_mfma_f32_16x16x32_bf16(af[kk], bf, acc[n], 0, 0, 0);
        }
    __syncthreads();

    {
        float b1v[8];
        #pragma unroll
        for (int n = 0; n < 8; ++n) b1v[n] = b1[n * 16 + lr];
        #pragma unroll
        for (int n = 0; n < 8; ++n) {
            #pragma unroll
            for (int j = 0; j < 4; ++j) {
                float hv = fmaxf(acc[n][j] + b1v[n], 0.f);
                As[w * 16 + lg * 4 + j][n * 16 + lr] = (short)cvt_pk_bf16(hv, hv);
            }
        }
    }
    #pragma unroll
    for (int p = 0; p < 8; ++p) {
        int off = p * 2048 + tid * 8;
        short8 v = *(const short8*)(W2 + off);
        *(short8*)&Ws[off >> 7][off & 127] = v;
    }
    __syncthreads();

    #pragma unroll
    for (int kk = 0; kk < 4; ++kk)
        af[kk] = *(short8*)&As[w * 16 + lr][kk * 32 + lg * 8];
    #pragma unroll
    for (int n = 0; n < 8; ++n) acc[n] = (f32x4){0.f, 0.f, 0.f, 0.f};
    #pragma unroll
    for (int n = 0; n < 8; ++n)
        #pragma unroll
        for (int kk = 0; kk < 4; ++kk) {
            short8 bf = *(short8*)&Ws[n * 16 + lr][kk * 32 + lg * 8];
            acc[n] = __builtin_amdgcn_mfma_f32_16x16x32_bf16(af[kk], bf, acc[n], 0, 0, 0);
        }

    float bv[8], lsv[8], lbv[8];
    #pragma unroll
    for (int n = 0; n < 8; ++n) {
        int col = n * 16 + lr;
        bv[n] = b2[col]; lsv[n] = ls[col]; lbv[n] = lb[col];
    }
    #pragma unroll
    for (int j = 0; j < 4; ++j) {
        int row = row0 + w * 16 + lg * 4 + j;
        float xv[8]; float sum = 0.f;
        #pragma unroll
        for (int n = 0; n < 8; ++n) {
            xv[n] = acc[n][j] + bv[n] + h[(size_t)row * 128 + n * 16 + lr];
            sum += xv[n];
        }
        sum += __shfl_xor(sum, 1); sum += __shfl_xor(sum, 2);
        sum += __shfl_xor(sum, 4); sum += __shfl_xor(sum, 8);
        float mean = sum * (1.f / 128.f);
        float vs = 0.f;
        #pragma unroll
        for (int n = 0; n < 8; ++n) { float dd = xv[n] - mean; vs += dd * dd; }
        vs += __shfl_xor(vs, 1); vs += __shfl_xor(vs, 2);
        vs += __shfl_xor(vs, 4); vs += __shfl_xor(vs, 8);
        float inv = rsqrtf(vs * (1.f / 128.f) + 1e-5f);
        #pragma unroll
        for (int n = 0; n < 8; ++n)
            h[(size_t)row * 128 + n * 16 + lr] = (xv[n] - mean) * inv * lsv[n] + lbv[n];
    }
}

// ---------------- MFMA bf16 flash attention (R13 structure + paired-V + setprio) ----------------
// Swizzled K/V LDS, reg-P via k-permutation, 32 q/wave, double buffer,
// raw v_exp_f32, compile-time buffer offsets. V loaded PRE-PAIRED from vbuf.
__global__ __launch_bounds__(256) void attn_mfma_k(
    const ushort* __restrict__ qkv, const unsigned* __restrict__ vbuf,
    ushort* __restrict__ o)
{
    // layout: K buf0 @0, K buf1 @4096, V buf0 @8192, V buf1 @12288
    __shared__ __align__(16) char smem[16384];

    int bid = blockIdx.x;
    int b  = bid & 7;
    int qt = (bid >> 3) & 15;
    int hd = bid >> 7;
    int tid  = threadIdx.x;
    int wave = tid >> 6;
    int lane = tid & 63;
    int lg = lane >> 4, lr = lane & 15;

    const ushort* base = qkv + (size_t)b * LL * 384;
    int qr0 = qt * 128 + wave * 32;

    short8 qfA = *(const short8*)(base + (size_t)(qr0 + lr) * 384 + hd * 32 + lg * 8);
    short8 qfB = *(const short8*)(base + (size_t)(qr0 + 16 + lr) * 384 + hd * 32 + lg * 8);

    // ---- precomputed addresses (buffer-relative byte offsets) ----
    int kk = tid >> 2, ks = tid & 3;
    int krow = kk & 31;
    int kchk = (((kk >> 5) << 2) + ks) ^ (krow & 7);
    int kwo = krow * 128 + (kchk << 4);
    const ushort* kptr = base + (size_t)kk * 384 + 128 + hd * 32 + ks * 8;

    int k2 = (tid & 31) * 2, d0 = (tid >> 5) * 4;
    int rl = k2 & 31;
    int colp = (k2 >> 5) * 32 + ((rl >> 2) & 3) * 8 + (rl >> 4) * 4 + (rl & 3);
    int vchunk = colp >> 3;
    int vinb   = (colp * 2) & 15;
    int vwo0 = (d0+0)*128 + (((vchunk ^ ((d0+0)&7)) << 4) | vinb);
    int vwo1 = (d0+1)*128 + (((vchunk ^ ((d0+1)&7)) << 4) | vinb);
    int vwo2 = (d0+2)*128 + (((vchunk ^ ((d0+2)&7)) << 4) | vinb);
    int vwo3 = (d0+3)*128 + (((vchunk ^ ((d0+3)&7)) << 4) | vinb);
    // paired-V source: vbuf[(b,hd)][lpair][d], uint per (keypair, d)
    const unsigned* vptr = vbuf + (((size_t)b * 4 + hd) * 1024 + (k2 >> 1)) * 32 + d0;

    int kro[4];
    #pragma unroll
    for (int n = 0; n < 4; ++n) {
        int r = ((n & 1) << 4) + lr;
        int c = (((n >> 1) << 2) + lg) ^ (r & 7);
        kro[n] = r * 128 + (c << 4);
    }
    int sx = (lg ^ (lr & 7)) << 4;
    int sy = ((4 + lg) ^ (lr & 7)) << 4;
    int vro0 = lr * 128 + sx;
    int vro1 = (16 + lr) * 128 + sx;
    int vro2 = lr * 128 + sy;
    int vro3 = (16 + lr) * 128 + sy;

    f32x4 OfA[2] = {}, OfB[2] = {};
    f32x4 OlA = {}, OlB = {};
    const f32x4 zero4 = {0.f, 0.f, 0.f, 0.f};
    short8 ones;
    #pragma unroll
    for (int e = 0; e < 8; ++e) ones[e] = (short)0x3F80;   // bf16 1.0

    const int TSTR = 64 * 384;       // qkv row stride per tile
    const int VSTR = 32 * 32;        // vbuf uints per tile (32 keypairs x 32 d)
    const ushort* knext = kptr;
    const unsigned* vnext = vptr;

    // prologue: tile 0 -> buffers @0 (K) and @8192 (V)
    {
        short8 kreg = *(const short8*)knext;
        uint4 vv = *(const uint4*)vnext;
        knext += TSTR; vnext += VSTR;
        *(short8*)(smem + 0 + kwo) = kreg;
        *(unsigned*)(smem + 8192 + vwo0) = vv.x;
        *(unsigned*)(smem + 8192 + vwo1) = vv.y;
        *(unsigned*)(smem + 8192 + vwo2) = vv.z;
        *(unsigned*)(smem + 8192 + vwo3) = vv.w;
    }
    __syncthreads();

#define ATTN_TILE(KRB, VRB, KWB, VWB, LAST) do {                              \
    short8 kreg_; uint4 vv_;                                                  \
    if (!(LAST)) {                                                            \
        kreg_ = *(const short8*)knext;                                        \
        vv_   = *(const uint4*)vnext;                                         \
        knext += TSTR; vnext += VSTR;                                         \
    }                                                                         \
    short8 kf0_ = *(const short8*)(smem + (KRB) + kro[0]);                    \
    short8 kf1_ = *(const short8*)(smem + (KRB) + kro[1]);                    \
    short8 kf2_ = *(const short8*)(smem + (KRB) + kro[2]);                    \
    short8 kf3_ = *(const short8*)(smem + (KRB) + kro[3]);                    \
    __builtin_amdgcn_s_setprio(1);                                            \
    f32x4 SA0_ = __builtin_amdgcn_mfma_f32_16x16x32_bf16(kf0_, qfA, zero4,0,0,0); \
    f32x4 SA1_ = __builtin_amdgcn_mfma_f32_16x16x32_bf16(kf1_, qfA, zero4,0,0,0); \
    f32x4 SA2_ = __builtin_amdgcn_mfma_f32_16x16x32_bf16(kf2_, qfA, zero4,0,0,0); \
    f32x4 SA3_ = __builtin_amdgcn_mfma_f32_16x16x32_bf16(kf3_, qfA, zero4,0,0,0); \
    f32x4 SB0_ = __builtin_amdgcn_mfma_f32_16x16x32_bf16(kf0_, qfB, zero4,0,0,0); \
    f32x4 SB1_ = __builtin_amdgcn_mfma_f32_16x16x32_bf16(kf1_, qfB, zero4,0,0,0); \
    f32x4 SB2_ = __builtin_amdgcn_mfma_f32_16x16x32_bf16(kf2_, qfB, zero4,0,0,0); \
    f32x4 SB3_ = __builtin_amdgcn_mfma_f32_16x16x32_bf16(kf3_, qfB, zero4,0,0,0); \
    union { uint4 u; short8 s; } paA0_, paA1_, paB0_, paB1_;                  \
    paA0_.u.x = cvt_pk_bf16(fexp2(SA0_[0]), fexp2(SA0_[1]));                  \
    paA0_.u.y = cvt_pk_bf16(fexp2(SA0_[2]), fexp2(SA0_[3]));                  \
    paA0_.u.z = cvt_pk_bf16(fexp2(SA1_[0]), fexp2(SA1_[1]));                  \
    paA0_.u.w = cvt_pk_bf16(fexp2(SA1_[2]), fexp2(SA1_[3]));                  \
    paA1_.u.x = cvt_pk_bf16(fexp2(SA2_[0]), fexp2(SA2_[1]));                  \
    paA1_.u.y = cvt_pk_bf16(fexp2(SA2_[2]), fexp2(SA2_[3]));                  \
    paA1_.u.z = cvt_pk_bf16(fexp2(SA3_[0]), fexp2(SA3_[1]));                  \
    paA1_.u.w = cvt_pk_bf16(fexp2(SA3_[2]), fexp2(SA3_[3]));                  \
    paB0_.u.x = cvt_pk_bf16(fexp2(SB0_[0]), fexp2(SB0_[1]));                  \
    paB0_.u.y = cvt_pk_bf16(fexp2(SB0_[2]), fexp2(SB0_[3]));                  \
    paB0_.u.z = cvt_pk_bf16(fexp2(SB1_[0]), fexp2(SB1_[1]));                  \
    paB0_.u.w = cvt_pk_bf16(fexp2(SB1_[2]), fexp2(SB1_[3]));                  \
    paB1_.u.x = cvt_pk_bf16(fexp2(SB2_[0]), fexp2(SB2_[1]));                  \
    paB1_.u.y = cvt_pk_bf16(fexp2(SB2_[2]), fexp2(SB2_[3]));                  \
    paB1_.u.z = cvt_pk_bf16(fexp2(SB3_[0]), fexp2(SB3_[1]));                  \
    paB1_.u.w = cvt_pk_bf16(fexp2(SB3_[2]), fexp2(SB3_[3]));                  \
    short8 vb00_ = *(const short8*)(smem + (VRB) + vro0);                     \
    short8 vb01_ = *(const short8*)(smem + (VRB) + vro1);                     \
    short8 vb10_ = *(const short8*)(smem + (VRB) + vro2);                     \
    short8 vb11_ = *(const short8*)(smem + (VRB) + vro3);                     \
    OlA    = __builtin_amdgcn_mfma_f32_16x16x32_bf16(paA0_.s, ones,  OlA,   0,0,0); \
    OfA[0] = __builtin_amdgcn_mfma_f32_16x16x32_bf16(paA0_.s, vb00_, OfA[0],0,0,0); \
    OfA[1] = __builtin_amdgcn_mfma_f32_16x16x32_bf16(paA0_.s, vb01_, OfA[1],0,0,0); \
    OlA    = __builtin_amdgcn_mfma_f32_16x16x32_bf16(paA1_.s, ones,  OlA,   0,0,0); \
    OfA[0] = __builtin_amdgcn_mfma_f32_16x16x32_bf16(paA1_.s, vb10_, OfA[0],0,0,0); \
    OfA[1] = __builtin_amdgcn_mfma_f32_16x16x32_bf16(paA1_.s, vb11_, OfA[1],0,0,0); \
    OlB    = __builtin_amdgcn_mfma_f32_16x16x32_bf16(paB0_.s, ones,  OlB,   0,0,0); \
    OfB[0] = __builtin_amdgcn_mfma_f32_16x16x32_bf16(paB0_.s, vb00_, OfB[0],0,0,0); \
    OfB[1] = __builtin_amdgcn_mfma_f32_16x16x32_bf16(paB0_.s, vb01_, OfB[1],0,0,0); \
    OlB    = __builtin_amdgcn_mfma_f32_16x16x32_bf16(paB1_.s, ones,  OlB,   0,0,0); \
    OfB[0] = __builtin_amdgcn_mfma_f32_16x16x32_bf16(paB1_.s, vb10_, OfB[0],0,0,0); \
    OfB[1] = __builtin_amdgcn_mfma_f32_16x16x32_bf16(paB1_.s, vb11_, OfB[1],0,0,0); \
    __builtin_amdgcn_s_setprio(0);                                            \
    if (!(LAST)) {                                                            \
        *(short8*)(smem + (KWB) + kwo) = kreg_;                               \
        *(unsigned*)(smem + (VWB) + vwo0) = vv_.x;                            \
        *(unsigned*)(smem + (VWB) + vwo1) = vv_.y;                            \
        *(unsigned*)(smem + (VWB) + vwo2) = vv_.z;                            \
        *(unsigned*)(smem + (VWB) + vwo3) = vv_.w;                            \
    }                                                                         \
    __syncthreads();                                                          \
} while (0)

    #pragma unroll 1
    for (int t = 0; t < 32; t += 2) {
        ATTN_TILE(0,    8192,  4096, 12288, false);
        ATTN_TILE(4096, 12288, 0,    8192,  (t + 2 >= 32));
    }
#undef ATTN_TILE

    #pragma unroll
    for (int j = 0; j < 4; ++j) {
        float invA = 1.f / OlA[j];
        int qA = qr0 + lg * 4 + j;
        size_t obA = ((size_t)b * LL + qA) * DMODEL + hd * 32;
        float a0 = OfA[0][j] * invA, a1 = OfA[1][j] * invA;
        o[obA + lr]      = (ushort)cvt_pk_bf16(a0, a0);
        o[obA + 16 + lr] = (ushort)cvt_pk_bf16(a1, a1);
        float invB = 1.f / OlB[j];
        int qB = qr0 + 16 + lg * 4 + j;
        size_t obB = ((size_t)b * LL + qB) * DMODEL + hd * 32;
        float b0 = OfB[0][j] * invB, b1 = OfB[1][j] * invB;
        o[obB + lr]      = (ushort)cvt_pk_bf16(b0, b0);
        o[obB + 16 + lr] = (ushort)cvt_pk_bf16(b1, b1);
    }
}

// ---------------- x_proj bf16 MFMA: dbc[M,40] = xm[M,256] @ W[40,256]^T ----------------
__global__ __launch_bounds__(256) void xproj_bf16_k(
    const float* __restrict__ A, const ushort* __restrict__ W16,
    float* __restrict__ C)
{
    __shared__ __align__(16) short As[64][264];
    __shared__ __align__(16) short Ws[48][264];
    int tid = threadIdx.x;
    int w = tid >> 6, lane = tid & 63, lg = lane >> 4, lr = lane & 15;
    int row0 = blockIdx.x * 64;

    const float* Ab = A + (size_t)row0 * 256;
    #pragma unroll
    for (int p = 0; p < 16; ++p) {
        int off = p * 1024 + tid * 4;
        float4 v = *(const float4*)(Ab + off);
        uint2 pw; pw.x = cvt_pk_bf16(v.x, v.y); pw.y = cvt_pk_bf16(v.z, v.w);
        *(uint2*)&As[off >> 8][off & 255] = pw;
    }
    #pragma unroll
    for (int p = 0; p < 6; ++p) {
        int off = p * 2048 + tid * 8;
        int r = off >> 8, c = off & 255;
        short8 v = {};
        if (r < 40) v = *(const short8*)(W16 + (size_t)r * 256 + c);
        *(short8*)&Ws[r][c] = v;
    }
    __syncthreads();

    short8 af[8];
    #pragma unroll
    for (int kk = 0; kk < 8; ++kk)
        af[kk] = *(short8*)&As[w * 16 + lr][kk * 32 + lg * 8];

    f32x4 acc[3];
    #pragma unroll
    for (int n = 0; n < 3; ++n) acc[n] = (f32x4){0.f, 0.f, 0.f, 0.f};
    #pragma unroll
    for (int n = 0; n < 3; ++n)
        #pragma unroll
        for (int kk = 0; kk < 8; ++kk) {
            short8 bf = *(short8*)&Ws[n * 16 + lr][kk * 32 + lg * 8];
            acc[n] = __builtin_amdgcn_mfma_f32_16x16x32_bf16(af[kk], bf, acc[n], 0, 0, 0);
        }
    #pragma unroll
    for (int n = 0; n < 3; ++n) {
        int col = n * 16 + lr;
        if (col < 40) {
            #pragma unroll
            for (int j = 0; j < 4; ++j) {
                int row = row0 + w * 16 + lg * 4 + j;
                C[(size_t)row * 40 + col] = acc[n][j];
            }
        }
    }
}

// ---------------- causal depthwise conv(4) + silu ----------------
__global__ __launch_bounds__(256) void conv_silu_k(
    const float* __restrict__ xz, const float* __restrict__ cw,
    const float* __restrict__ cb, float* __restrict__ xm)
{
    int idx = blockIdx.x * 256 + threadIdx.x;
    int d   = idx & 255;
    int row = idx >> 8;
    int l   = row & (LL - 1);
    float a = cb[d];
    #pragma unroll
    for (int t = 0; t < 4; ++t) {
        int ll = l - 3 + t;
        if (ll >= 0) a += cw[d * 4 + t] * xz[(size_t)(row - 3 + t) * 512 + d];
    }
    float sg = 1.f / (1.f + expf(-a));
    xm[idx] = a * sg;
}

// ---------------- dt = softplus(dbc[:, :8] @ dt_w^T + dt_b), 4 rows/block ----------------
__global__ __launch_bounds__(256) void dtproj_k(
    const float* __restrict__ dbc, const float* __restrict__ w,
    const float* __restrict__ bias, float* __restrict__ dt)
{
    int row0 = blockIdx.x * 4, n = threadIdx.x;
    __shared__ float dv[4][8];
    if (n < 32) dv[n >> 3][n & 7] = dbc[(size_t)(row0 + (n >> 3)) * 40 + (n & 7)];
    __syncthreads();
    float bv = bias[n];
    float wv[8];
    #pragma unroll
    for (int k = 0; k < 8; ++k) wv[k] = w[n * 8 + k];
    #pragma unroll
    for (int r = 0; r < 4; ++r) {
        float a = bv;
        #pragma unroll
        for (int k = 0; k < 8; ++k) a += dv[r][k] * wv[k];
        float sp = fmaxf(a, 0.f) + log1pf(expf(-fabsf(a)));
        dt[(size_t)(row0 + r) * 256 + n] = sp;
    }
}

// ---------------- scan pass 1: thread=(d, sh), 8 states; coalesced loads ----------------
__global__ __launch_bounds__(512) void scan1_k(
    const float* __restrict__ dt, const float* __restrict__ xm,
    const float* __restrict__ dbc, const float* __restrict__ A_log,
    float* __restrict__ Asum, float* __restrict__ Bsum)
{
    int blk = blockIdx.x;             // b*32 + c
    int c = blk & 31, b = blk >> 5;
    int tid = threadIdx.x;
    int d = tid >> 1, sh = tid & 1;
    float Av2[8];
    {
        float4 a0 = *(const float4*)(A_log + d * 16 + sh * 8);
        float4 a1 = *(const float4*)(A_log + d * 16 + sh * 8 + 4);
        Av2[0] = -expf(a0.x) * 1.4426950408889634f;
        Av2[1] = -expf(a0.y) * 1.4426950408889634f;
        Av2[2] = -expf(a0.z) * 1.4426950408889634f;
        Av2[3] = -expf(a0.w) * 1.4426950408889634f;
        Av2[4] = -expf(a1.x) * 1.4426950408889634f;
        Av2[5] = -expf(a1.y) * 1.4426950408889634f;
        Av2[6] = -expf(a1.z) * 1.4426950408889634f;
        Av2[7] = -expf(a1.w) * 1.4426950408889634f;
    }
    float aarg[8] = {}, Bacc[8] = {};
    __shared__ float Bst[CH][16];
    size_t rowb = (size_t)b * LL + c * CH;
    {
        int e = tid * 2;
        int j = e >> 4, col = e & 15;
        float2 v = *(const float2*)(dbc + (rowb + j) * 40 + 8 + col);
        Bst[j][col] = v.x; Bst[j][col + 1] = v.y;
    }
    __syncthreads();
    #pragma unroll 4
    for (int j = 0; j < CH; ++j) {
        size_t rr = rowb + j;
        float dtv = dt[rr * 256 + d];
        float xmv = xm[rr * 256 + d];
        float dtxm = dtv * xmv;
        float4 b0 = *(const float4*)&Bst[j][sh * 8];
        float4 b1 = *(const float4*)&Bst[j][sh * 8 + 4];
        float bb[8] = {b0.x, b0.y, b0.z, b0.w, b1.x, b1.y, b1.z, b1.w};
        #pragma unroll
        for (int k = 0; k < 8; ++k) {
            float arg = dtv * Av2[k];
            Bacc[k] = Bacc[k] * fexp2(arg) + bb[k] * dtxm;
            aarg[k] += arg;
        }
    }
    #pragma unroll
    for (int k = 0; k < 8; ++k) {
        size_t oo = ((size_t)(blk * 16 + sh * 8 + k)) * 256 + d;
        Asum[oo] = fexp2(aarg[k]);
        Bsum[oo] = Bacc[k];
    }
}

// ---------------- scan mid ----------------
__global__ __launch_bounds__(256) void scan_mid_k(
    const float* __restrict__ Asum, const float* __restrict__ Bsum,
    float* __restrict__ hinit)
{
    int b = blockIdx.x >> 4, s = blockIdx.x & 15;
    int d = threadIdx.x;
    float h = 0.f;
    #pragma unroll 4
    for (int c = 0; c < NCHUNK; ++c) {
        size_t oo = ((size_t)((b * 32 + c) * 16 + s)) * 256 + d;
        hinit[oo] = h;
        h = Asum[oo] * h + Bsum[oo];
    }
}

// ---------------- scan pass 2 + gate + pool: thread=(d, sh), 8 states ----------------
__global__ __launch_bounds__(512) void scan2_k(
    const float* __restrict__ dt, const float* __restrict__ xm,
    const float* __restrict__ dbc, const float* __restrict__ A_log,
    const float* __restrict__ hinit, const float* __restrict__ xz,
    const float* __restrict__ dsk, float* __restrict__ part)
{
    int blk = blockIdx.x;
    int c = blk & 31, b = blk >> 5;
    int tid = threadIdx.x;
    int d = tid >> 1, sh = tid & 1;
    float Av2[8];
    {
        float4 a0 = *(const float4*)(A_log + d * 16 + sh * 8);
        float4 a1 = *(const float4*)(A_log + d * 16 + sh * 8 + 4);
        Av2[0] = -expf(a0.x) * 1.4426950408889634f;
        Av2[1] = -expf(a0.y) * 1.4426950408889634f;
        Av2[2] = -expf(a0.z) * 1.4426950408889634f;
        Av2[3] = -expf(a0.w) * 1.4426950408889634f;
        Av2[4] = -expf(a1.x) * 1.4426950408889634f;
        Av2[5] = -expf(a1.y) * 1.4426950408889634f;
        Av2[6] = -expf(a1.z) * 1.4426950408889634f;
        Av2[7] = -expf(a1.w) * 1.4426950408889634f;
    }
    float hs[8];
    #pragma unroll
    for (int k = 0; k < 8; ++k)
        hs[k] = hinit[((size_t)(blk * 16 + sh * 8 + k)) * 256 + d];
    float dskv = dsk[d];
    float psum = 0.f;
    __shared__ float Bst[CH][16], Cst[CH][16];
    size_t rowb = (size_t)b * LL + c * CH;
    {
        int e = tid * 2;
        int j = e >> 4, col = e & 15;
        float2 v = *(const float2*)(dbc + (rowb + j) * 40 + 8 + col);
        Bst[j][col] = v.x; Bst[j][col + 1] = v.y;
        float2 u = *(const float2*)(dbc + (rowb + j) * 40 + 24 + col);
        Cst[j][col] = u.x; Cst[j][col + 1] = u.y;
    }
    __syncthreads();
    #pragma unroll 2
    for (int j = 0; j < CH; ++j) {
        size_t rr = rowb + j;
        float dtv = dt[rr * 256 + d];
        float xmv = xm[rr * 256 + d];
        float dtxm = dtv * xmv;
        float4 b0 = *(const float4*)&Bst[j][sh * 8];
        float4 b1 = *(const float4*)&Bst[j][sh * 8 + 4];
        float4 c0 = *(const float4*)&Cst[j][sh * 8];
        float4 c1 = *(const float4*)&Cst[j][sh * 8 + 4];
        float bb[8] = {b0.x, b0.y, b0.z, b0.w, b1.x, b1.y, b1.z, b1.w};
        float cc[8] = {c0.x, c0.y, c0.z, c0.w, c1.x, c1.y, c1.z, c1.w};
        float yv = 0.f;
        #pragma unroll
        for (int k = 0; k < 8; ++k) {
            float dA = fexp2(dtv * Av2[k]);
            hs[k] = hs[k] * dA + bb[k] * dtxm;
            yv += hs[k] * cc[k];
        }
        yv += __shfl_xor(yv, 1);
        float zv = xz[rr * 512 + 256 + d];
        float sg = zv / (1.f + __expf(-zv));
        psum += (yv + xmv * dskv) * sg;
    }
    if (sh == 0) part[(size_t)blk * 256 + d] = psum;   // part[b][c][d]
}

// ---------------- final: pooled @ out_proj^T -> mlp2 ----------------
__global__ __launch_bounds__(128) void final_k(
    const float* __restrict__ part, const float* __restrict__ opw,
    const float* __restrict__ w1, const float* __restrict__ b1,
    const float* __restrict__ w2, const float* __restrict__ b2,
    float* __restrict__ out)
{
    int b = blockIdx.x, t = threadIdx.x;
    __shared__ float pg[256];
    __shared__ float pooled[128];
    __shared__ float hid[32];
    for (int k = t; k < 256; k += 128) {
        float sm = 0.f;
        #pragma unroll
        for (int c = 0; c < NCHUNK; ++c)
            sm += part[(size_t)(b * 32 + c) * 256 + k];
        pg[k] = sm * (1.f / 2048.f);
    }
    __syncthreads();
    float a = 0.f;
    for (int k = 0; k < 256; ++k) a += pg[k] * opw[(size_t)t * DIN + k];
    pooled[t] = a;
    __syncthreads();
    if (t < 32) {
        float hh = b1[t];
        for (int d2 = 0; d2 < 128; ++d2) hh += pooled[d2] * w1[t * 128 + d2];
        hid[t] = fmaxf(hh, 0.f);
    }
    __syncthreads();
    if (t == 0) {
        float o = b2[0];
        #pragma unroll
        for (int j = 0; j < 32; ++j) o += hid[j] * w2[j];
        out[b] = o;
    }
}

extern "C" void kernel_launch(void* const* d_in, const int* in_sizes, int n_in,
                              void* d_out, int out_size, void* d_ws, size_t ws_size,
                              hipStream_t stream)
{
    const float* x          = (const float*)d_in[0];
    const float* mlp1_w     = (const float*)d_in[1];
    const float* mlp1_b     = (const float*)d_in[2];
    const float* qkv_w      = (const float*)d_in[3];
    const float* qkv_b      = (const float*)d_in[4];
    const float* attn_out_w = (const float*)d_in[5];
    const float* attn_out_b = (const float*)d_in[6];
    const float* ln1_s      = (const float*)d_in[7];
    const float* ln1_b      = (const float*)d_in[8];
    const float* ffw_w1     = (const float*)d_in[9];
    const float* ffw_b1     = (const float*)d_in[10];
    const float* ffw_w2     = (const float*)d_in[11];
    const float* ffw_b2     = (const float*)d_in[12];
    const float* ln2_s      = (const float*)d_in[13];
    const float* ln2_b      = (const float*)d_in[14];
    const float* in_proj_w  = (const float*)d_in[15];
    const float* conv_w     = (const float*)d_in[16];
    const float* conv_b     = (const float*)d_in[17];
    const float* x_proj_w   = (const float*)d_in[18];
    const float* dt_proj_w  = (const float*)d_in[19];
    const float* dt_proj_b  = (const float*)d_in[20];
    const float* A_log      = (const float*)d_in[21];
    const float* D_skip     = (const float*)d_in[22];
    const float* out_proj_w = (const float*)d_in[23];
    const float* mlp2_w1    = (const float*)d_in[24];
    const float* mlp2_b1    = (const float*)d_in[25];
    const float* mlp2_w2    = (const float*)d_in[26];
    const float* mlp2_b2    = (const float*)d_in[27];
    float* out = (float*)d_out;
    float* ws  = (float*)d_ws;

    // workspace layout (floats)
    float* h     = ws;                              // BLROWS*128
    float* xz    = h    + (size_t)BLROWS * DMODEL;  // BLROWS*512  (qkv16 alias)
    float* t1    = xz   + (size_t)BLROWS * 512;     // BLROWS*128 (attn-out bf16 alias / dt)
    float* t2    = t1   + (size_t)BLROWS * DMODEL;  // BLROWS*128
    float* xm    = t2   + (size_t)BLROWS * DMODEL;  // BLROWS*256
    float* dbc   = xm   + (size_t)BLROWS * DIN;     // BLROWS*40
    float* part2 = dbc  + (size_t)BLROWS * 40;      // 8*32*256
    float* Asum  = part2 + 8 * 32 * 256;            // 8*32*16*256
    float* Bsum  = Asum + 8 * 32 * 16 * 256;
    float* hini  = Bsum + 8 * 32 * 16 * 256;
    ushort* w16  = (ushort*)(hini + 8 * 32 * 16 * 256);
    ushort* qkvw16 = w16;                 // 6*384*128 = 294912
    ushort* aow16  = w16 + 294912;        // 98304
    ushort* f1w16  = w16 + 393216;        // 98304
    ushort* f2w16  = w16 + 491520;        // 98304
    ushort* ipw16  = w16 + 589824;        // 65536
    ushort* xpw16  = w16 + 655360;        // 10240
    unsigned* vbuf = (unsigned*)(w16 + 665600);   // 8*4*1024*32 uints = 4 MB
    ushort* qkv16 = (ushort*)xz;
    ushort* t1u   = (ushort*)t1;          // attn out bf16
    float* dtb  = t1;                     // dt (fp32) in mamba phase
    (void)t2;

    // weight preconversion
    wcvt_k<<<(294912/4 + 255)/256, 256, 0, stream>>>(qkv_w, qkvw16, 294912/4);
    wcvt_k<<<(98304/4 + 255)/256, 256, 0, stream>>>(attn_out_w, aow16, 98304/4);
    wcvt_k<<<(98304/4 + 255)/256, 256, 0, stream>>>(ffw_w1, f1w16, 98304/4);
    wcvt_k<<<(98304/4 + 255)/256, 256, 0, stream>>>(ffw_w2, f2w16, 98304/4);
    wcvt_k<<<(65536/4 + 255)/256, 256, 0, stream>>>(in_proj_w, ipw16, 65536/4);
    wcvt_k<<<(10240/4 + 255)/256, 256, 0, stream>>>(x_proj_w, xpw16, 10240/4);

    mlp1_pe_k<<<(BLROWS * DMODEL) / 256, 256, 0, stream>>>(x, mlp1_w, mlp1_b, h);

    for (int i = 0; i < NLAYERS; ++i) {
        gemm_qkv_k<<<dim3(3, 256), 256, 0, stream>>>(
            h, qkvw16 + (size_t)i * 384 * 128, qkv_b + i * 384, qkv16, vbuf);
        attn_mfma_k<<<512, 256, 0, stream>>>(qkv16, vbuf, t1u);
        gemm_ln_k<<<256, 256, 0, stream>>>(
            t1u, aow16 + (size_t)i * 128 * 128, attn_out_b + i * 128, h,
            ln1_s + i * 128, ln1_b + i * 128);
        ffw_ln_k<<<256, 256, 0, stream>>>(
            h, f1w16 + (size_t)i * 128 * 128, ffw_b1 + i * 128,
            f2w16 + (size_t)i * 128 * 128, ffw_b2 + i * 128,
            ln2_s + i * 128, ln2_b + i * 128);
    }

    // Mamba block
    gemm_bf16_k<<<dim3(4, 256), 256, 0, stream>>>(h, ipw16, xz, 512);
    conv_silu_k<<<(BLROWS * DIN) / 256, 256, 0, stream>>>(xz, conv_w, conv_b, xm);
    xproj_bf16_k<<<256, 256, 0, stream>>>(xm, xpw16, dbc);
    dtproj_k<<<BLROWS / 4, 256, 0, stream>>>(dbc, dt_proj_w, dt_proj_b, dtb);
    scan1_k<<<256, 512, 0, stream>>>(dtb, xm, dbc, A_log, Asum, Bsum);
    scan_mid_k<<<128, 256, 0, stream>>>(Asum, Bsum, hini);
    scan2_k<<<256, 512, 0, stream>>>(dtb, xm, dbc, A_log, hini, xz, D_skip, part2);
    final_k<<<8, 128, 0, stream>>>(part2, out_proj_w, mlp2_w1, mlp2_b1, mlp2_w2, mlp2_b2, out);
}